// Round 1
// baseline (320.697 us; speedup 1.0000x reference)
//
#include <hip/hip_runtime.h>

#define BATCHES 8
#define NPTS    100000
#define NPOINT  64
#define BPB     16                    // blocks per batch
#define NTHREADS 1024
#define TPB     (BPB * NTHREADS)      // threads per batch = 16384
#define KMAX    7                     // ceil(NPTS / TPB)
#define TAILN   (NPTS - (KMAX - 1) * TPB)   // 1696 threads get a 7th point

// workspace layout (all zeroed per call by hipMemsetAsync)
#define WS_BARY_OFF 0                                   // [BATCHES][BPB][3] double
#define WS_SLOT_OFF (BATCHES * BPB * 3 * 8)             // 3072: [BATCHES][NPOINT] u64
#define WS_CNT_OFF  (WS_SLOT_OFF + BATCHES * NPOINT * 8)// 7168: [BATCHES][NPOINT+2] u32
#define WS_CTRL_BYTES (WS_CNT_OFF + BATCHES * (NPOINT + 2) * 4) // 9280

// contraction-free f32 squared distance, sum order (dx*dx + dy*dy) + dz*dz (numpy order)
__device__ __forceinline__ float sq3(float dx, float dy, float dz) {
    return __fadd_rn(__fadd_rn(__fmul_rn(dx, dx), __fmul_rn(dy, dy)), __fmul_rn(dz, dz));
}

__global__ __launch_bounds__(NTHREADS, 4)
void fps_kernel(const float* __restrict__ xyz, float* __restrict__ out,
                unsigned char* __restrict__ ws)
{
    double* baryPart = (double*)(ws + WS_BARY_OFF);
    unsigned long long* slots = (unsigned long long*)(ws + WS_SLOT_OFF);
    unsigned int* cnt = (unsigned int*)(ws + WS_CNT_OFF);

    const int b    = blockIdx.x >> 4;     // / BPB
    const int blk  = blockIdx.x & (BPB - 1);
    const int tid  = threadIdx.x;
    const int wid  = tid >> 6;
    const int lane = tid & 63;
    const int t    = blk * NTHREADS + tid;      // 0..TPB-1 within batch

    const float* xb = xyz + (size_t)b * NPTS * 3;

    __shared__ float centC[NPOINT][3];
    __shared__ double bred[16][3];
    __shared__ unsigned long long kred[16];
    __shared__ float s_c[3];
    __shared__ int s_far;

    float px[KMAX], py[KMAX], pz[KMAX], dist[KMAX];
    const int nk = (t < TAILN) ? KMAX : (KMAX - 1);

    // ---- load points into registers; accumulate double partial sums for mean ----
    double sx = 0.0, sy = 0.0, sz = 0.0;
    #pragma unroll
    for (int k = 0; k < KMAX; k++) {
        if (k < nk) {
            int p = t + k * TPB;
            float x = xb[p * 3 + 0], y = xb[p * 3 + 1], z = xb[p * 3 + 2];
            px[k] = x; py[k] = y; pz[k] = z; dist[k] = 1e10f;
            sx += (double)x; sy += (double)y; sz += (double)z;
        }
    }
    // wave reduce (deterministic tree), then cross-wave via LDS
    for (int off = 32; off > 0; off >>= 1) {
        sx += __shfl_down(sx, off); sy += __shfl_down(sy, off); sz += __shfl_down(sz, off);
    }
    if (lane == 0) { bred[wid][0] = sx; bred[wid][1] = sy; bred[wid][2] = sz; }
    __syncthreads();
    if (tid == 0) {
        double ax = 0, ay = 0, az = 0;
        for (int w = 0; w < 16; w++) { ax += bred[w][0]; ay += bred[w][1]; az += bred[w][2]; }
        double* dst = baryPart + ((size_t)b * BPB + blk) * 3;
        dst[0] = ax; dst[1] = ay; dst[2] = az;
        unsigned int* c = &cnt[b * (NPOINT + 2) + 0];
        __hip_atomic_fetch_add(c, 1u, __ATOMIC_ACQ_REL, __HIP_MEMORY_SCOPE_AGENT);
        while (__hip_atomic_load(c, __ATOMIC_ACQUIRE, __HIP_MEMORY_SCOPE_AGENT) < BPB)
            __builtin_amdgcn_s_sleep(2);
        // deterministic fixed-order sum of the 16 block partials
        double mx = 0, my = 0, mz = 0;
        for (int q = 0; q < BPB; q++) {
            const double* s2 = baryPart + ((size_t)b * BPB + q) * 3;
            mx += s2[0]; my += s2[1]; mz += s2[2];
        }
        s_c[0] = (float)(mx / (double)NPTS);
        s_c[1] = (float)(my / (double)NPTS);
        s_c[2] = (float)(mz / (double)NPTS);
    }
    __syncthreads();
    const float bx = s_c[0], by = s_c[1], bz = s_c[2];

    // ---- initial argmax over d0 (distance to barycenter) ----
    unsigned long long key = 0;
    #pragma unroll
    for (int k = 0; k < KMAX; k++) {
        if (k < nk) {
            int p = t + k * TPB;
            float d = sq3(__fsub_rn(px[k], bx), __fsub_rn(py[k], by), __fsub_rn(pz[k], bz));
            unsigned long long kk = (((unsigned long long)__float_as_uint(d)) << 32)
                                    | (unsigned)(0xFFFFFFFFu - (unsigned)p);
            if (kk > key) key = kk;
        }
    }
    for (int off = 32; off > 0; off >>= 1) {
        unsigned long long o = __shfl_down(key, off); if (o > key) key = o;
    }
    __syncthreads();
    if (lane == 0) kred[wid] = key;
    __syncthreads();
    if (tid == 0) {
        unsigned long long kb = kred[0];
        for (int w = 1; w < 16; w++) if (kred[w] > kb) kb = kred[w];
        unsigned long long* slot = &slots[b * NPOINT + 0];
        atomicMax(slot, kb);
        unsigned int* c = &cnt[b * (NPOINT + 2) + 1];
        __hip_atomic_fetch_add(c, 1u, __ATOMIC_ACQ_REL, __HIP_MEMORY_SCOPE_AGENT);
        while (__hip_atomic_load(c, __ATOMIC_ACQUIRE, __HIP_MEMORY_SCOPE_AGENT) < BPB)
            __builtin_amdgcn_s_sleep(2);
        unsigned long long r = __hip_atomic_load(slot, __ATOMIC_RELAXED, __HIP_MEMORY_SCOPE_AGENT);
        s_far = (int)(0xFFFFFFFFu - (unsigned)(r & 0xFFFFFFFFull));
    }
    // no barrier needed here; loop-top __syncthreads covers the broadcast

    // ---- 64 FPS iterations ----
    for (int i = 0; i < NPOINT; i++) {
        if (tid == 0) {
            int f = s_far;
            float cx = xb[f * 3 + 0], cy = xb[f * 3 + 1], cz = xb[f * 3 + 2];
            s_c[0] = cx; s_c[1] = cy; s_c[2] = cz;
            centC[i][0] = cx; centC[i][1] = cy; centC[i][2] = cz;
            if (blk == 0) {
                out[((size_t)b * NPOINT + i) * 3 + 0] = cx;
                out[((size_t)b * NPOINT + i) * 3 + 1] = cy;
                out[((size_t)b * NPOINT + i) * 3 + 2] = cz;
                out[(size_t)BATCHES * NPOINT * 3 + b * NPOINT + i] = (float)f;
            }
        }
        __syncthreads();
        if (i == NPOINT - 1) break;

        const int f = s_far;
        const float cx = s_c[0], cy = s_c[1], cz = s_c[2];
        key = 0;
        #pragma unroll
        for (int k = 0; k < KMAX; k++) {
            if (k < nk) {
                int p = t + k * TPB;
                float d = sq3(__fsub_rn(px[k], cx), __fsub_rn(py[k], cy), __fsub_rn(pz[k], cz));
                float nd = (p == f) ? 0.0f : fminf(dist[k], d);
                dist[k] = nd;
                unsigned long long kk = (((unsigned long long)__float_as_uint(nd)) << 32)
                                        | (unsigned)(0xFFFFFFFFu - (unsigned)p);
                if (kk > key) key = kk;
            }
        }
        for (int off = 32; off > 0; off >>= 1) {
            unsigned long long o = __shfl_down(key, off); if (o > key) key = o;
        }
        __syncthreads();
        if (lane == 0) kred[wid] = key;
        __syncthreads();
        if (tid == 0) {
            unsigned long long kb = kred[0];
            for (int w = 1; w < 16; w++) if (kred[w] > kb) kb = kred[w];
            unsigned long long* slot = &slots[b * NPOINT + (i + 1)];
            atomicMax(slot, kb);
            unsigned int* c = &cnt[b * (NPOINT + 2) + (i + 2)];
            __hip_atomic_fetch_add(c, 1u, __ATOMIC_ACQ_REL, __HIP_MEMORY_SCOPE_AGENT);
            while (__hip_atomic_load(c, __ATOMIC_ACQUIRE, __HIP_MEMORY_SCOPE_AGENT) < BPB)
                __builtin_amdgcn_s_sleep(2);
            unsigned long long r = __hip_atomic_load(slot, __ATOMIC_RELAXED, __HIP_MEMORY_SCOPE_AGENT);
            s_far = (int)(0xFFFFFFFFu - (unsigned)(r & 0xFFFFFFFFull));
        }
    }

    // ---- nearest-centroid assignment (centroids live in LDS) ----
    float* outClust = out + (size_t)BATCHES * NPOINT * 3 + (size_t)BATCHES * NPOINT;
    float bestd[KMAX]; int besti[KMAX];
    #pragma unroll
    for (int k = 0; k < KMAX; k++) { bestd[k] = 3.4e38f; besti[k] = 0; }
    for (int j = 0; j < NPOINT; j++) {
        float cx = centC[j][0], cy = centC[j][1], cz = centC[j][2];
        #pragma unroll
        for (int k = 0; k < KMAX; k++) {
            if (k < nk) {
                float d = sq3(__fsub_rn(px[k], cx), __fsub_rn(py[k], cy), __fsub_rn(pz[k], cz));
                if (d < bestd[k]) { bestd[k] = d; besti[k] = j; }   // strict < => first-index argmin
            }
        }
    }
    #pragma unroll
    for (int k = 0; k < KMAX; k++)
        if (k < nk) outClust[(size_t)b * NPTS + t + k * TPB] = (float)besti[k];
}

extern "C" void kernel_launch(void* const* d_in, const int* in_sizes, int n_in,
                              void* d_out, int out_size, void* d_ws, size_t ws_size,
                              hipStream_t stream) {
    const float* xyz = (const float*)d_in[0];
    float* out = (float*)d_out;
    // zero the barrier counters / argmax slots / barycenter partials every call
    hipMemsetAsync(d_ws, 0, WS_CTRL_BYTES, stream);
    fps_kernel<<<dim3(BATCHES * BPB), dim3(NTHREADS), 0, stream>>>(
        xyz, out, (unsigned char*)d_ws);
}

// Round 2
// 186.338 us; speedup vs baseline: 1.7210x; 1.7210x over previous
//
#include <hip/hip_runtime.h>

#define BATCHES 8
#define NPTS    100000
#define NPOINT  64
#define BPB     16                    // blocks per batch
#define NTHREADS 1024
#define TPB     (BPB * NTHREADS)      // threads per batch = 16384
#define KMAX    7                     // ceil(NPTS / TPB)
#define TAILN   (NPTS - (KMAX - 1) * TPB)   // threads with a 7th point

// workspace layout (zeroed per call by hipMemsetAsync)
#define WS_BARY_OFF 0                                    // [B][BPB][3] double = 3072 B
#define WS_CNT_OFF  3072                                 // [B] u32 = 32 B
#define WS_SLOT_OFF 4096                                 // [B][NPOINT][BPB] u64 = 65536 B
#define WS_CTRL_BYTES (WS_SLOT_OFF + BATCHES * NPOINT * BPB * 8)

// contraction-free f32 squared distance, numpy sum order (dx*dx + dy*dy) + dz*dz
__device__ __forceinline__ float sq3(float dx, float dy, float dz) {
    return __fadd_rn(__fadd_rn(__fmul_rn(dx, dx), __fmul_rn(dy, dy)), __fmul_rn(dz, dz));
}

__global__ __launch_bounds__(NTHREADS, 4)
void fps_kernel(const float* __restrict__ xyz, float* __restrict__ out,
                unsigned char* __restrict__ ws)
{
    double* baryPart = (double*)(ws + WS_BARY_OFF);
    unsigned int* cnt = (unsigned int*)(ws + WS_CNT_OFF);
    unsigned long long* slots = (unsigned long long*)(ws + WS_SLOT_OFF);

    const int b    = blockIdx.x >> 4;     // / BPB
    const int blk  = blockIdx.x & (BPB - 1);
    const int tid  = threadIdx.x;
    const int wid  = tid >> 6;
    const int lane = tid & 63;
    const int t    = blk * NTHREADS + tid;      // 0..TPB-1 within batch

    const float* xb = xyz + (size_t)b * NPTS * 3;

    __shared__ float centC[NPOINT][3];
    __shared__ double bred[16][3];
    __shared__ unsigned long long kred[16];
    __shared__ int s_far;

    float px[KMAX], py[KMAX], pz[KMAX], dist[KMAX];
    const int nk = (t < TAILN) ? KMAX : (KMAX - 1);

    // ---- load points into registers; accumulate double partial sums for mean ----
    double sx = 0.0, sy = 0.0, sz = 0.0;
    #pragma unroll
    for (int k = 0; k < KMAX; k++) {
        if (k < nk) {
            int p = t + k * TPB;
            float x = xb[p * 3 + 0], y = xb[p * 3 + 1], z = xb[p * 3 + 2];
            px[k] = x; py[k] = y; pz[k] = z; dist[k] = 1e10f;
            sx += (double)x; sy += (double)y; sz += (double)z;
        }
    }
    for (int off = 32; off > 0; off >>= 1) {
        sx += __shfl_down(sx, off); sy += __shfl_down(sy, off); sz += __shfl_down(sz, off);
    }
    if (lane == 0) { bred[wid][0] = sx; bred[wid][1] = sy; bred[wid][2] = sz; }
    __syncthreads();
    // one-time counter barrier for the barycenter (not on the per-round path)
    __shared__ float s_bc[3];
    if (tid == 0) {
        double ax = 0, ay = 0, az = 0;
        for (int w = 0; w < 16; w++) { ax += bred[w][0]; ay += bred[w][1]; az += bred[w][2]; }
        double* dst = baryPart + ((size_t)b * BPB + blk) * 3;
        dst[0] = ax; dst[1] = ay; dst[2] = az;
        __hip_atomic_fetch_add(&cnt[b], 1u, __ATOMIC_ACQ_REL, __HIP_MEMORY_SCOPE_AGENT);
        while (__hip_atomic_load(&cnt[b], __ATOMIC_ACQUIRE, __HIP_MEMORY_SCOPE_AGENT) < BPB)
            __builtin_amdgcn_s_sleep(2);
        double mx = 0, my = 0, mz = 0;
        for (int q = 0; q < BPB; q++) {       // deterministic fixed order
            const double* s2 = baryPart + ((size_t)b * BPB + q) * 3;
            mx += s2[0]; my += s2[1]; mz += s2[2];
        }
        s_bc[0] = (float)(mx / (double)NPTS);
        s_bc[1] = (float)(my / (double)NPTS);
        s_bc[2] = (float)(mz / (double)NPTS);
    }
    __syncthreads();
    const float bx = s_bc[0], by = s_bc[1], bz = s_bc[2];

    // ================= round 0: argmax of d0 (distance to barycenter) =================
    unsigned long long key = 0;
    #pragma unroll
    for (int k = 0; k < KMAX; k++) {
        if (k < nk) {
            int p = t + k * TPB;
            float d = sq3(__fsub_rn(px[k], bx), __fsub_rn(py[k], by), __fsub_rn(pz[k], bz));
            unsigned long long kk = (((unsigned long long)__float_as_uint(d)) << 32)
                                    | (unsigned)(0xFFFFFFFFu - (unsigned)p);
            if (kk > key) key = kk;
        }
    }
    // --- block reduce + contention-free global exchange (round r writes slots row r) ---
    #define EXCHANGE(ROUND)                                                                  \
    {                                                                                        \
        for (int off = 32; off > 0; off >>= 1) {                                             \
            unsigned long long o = __shfl_down(key, off); if (o > key) key = o;              \
        }                                                                                    \
        if (lane == 0) kred[wid] = key;                                                      \
        __syncthreads();                                                                     \
        if (wid == 0) {                                                                      \
            unsigned long long v = (lane < 16) ? kred[lane] : 0ull;                          \
            for (int m = 8; m > 0; m >>= 1) {                                                \
                unsigned long long o = __shfl_xor(v, m, 16); if (o > v) v = o;               \
            }                                                                                \
            unsigned long long* row = &slots[((size_t)b * NPOINT + (ROUND)) * BPB];          \
            if (lane == 0)                                                                   \
                __hip_atomic_store(&row[blk], v, __ATOMIC_RELAXED, __HIP_MEMORY_SCOPE_AGENT);\
            unsigned long long w = 0;                                                        \
            if (lane < BPB) {                                                                \
                while ((w = __hip_atomic_load(&row[lane], __ATOMIC_RELAXED,                  \
                                              __HIP_MEMORY_SCOPE_AGENT)) == 0ull)           \
                    __builtin_amdgcn_s_sleep(1);                                             \
            }                                                                                \
            for (int m = 8; m > 0; m >>= 1) {                                                \
                unsigned long long o = __shfl_xor(w, m, 16); if (o > w) w = o;               \
            }                                                                                \
            if (lane == 0)                                                                   \
                s_far = (int)(0xFFFFFFFFu - (unsigned)(w & 0xFFFFFFFFull));                  \
        }                                                                                    \
    }
    EXCHANGE(0)

    // ================= 64 FPS iterations =================
    for (int i = 0; i < NPOINT; i++) {
        __syncthreads();                       // publishes s_far to the whole block
        const int f = s_far;
        const float cx = xb[f * 3 + 0], cy = xb[f * 3 + 1], cz = xb[f * 3 + 2];
        if (tid == 0) {
            centC[i][0] = cx; centC[i][1] = cy; centC[i][2] = cz;
            if (blk == 0) {
                out[((size_t)b * NPOINT + i) * 3 + 0] = cx;
                out[((size_t)b * NPOINT + i) * 3 + 1] = cy;
                out[((size_t)b * NPOINT + i) * 3 + 2] = cz;
                out[(size_t)BATCHES * NPOINT * 3 + b * NPOINT + i] = (float)f;
            }
        }
        if (i == NPOINT - 1) break;

        key = 0;
        #pragma unroll
        for (int k = 0; k < KMAX; k++) {
            if (k < nk) {
                int p = t + k * TPB;
                float d = sq3(__fsub_rn(px[k], cx), __fsub_rn(py[k], cy), __fsub_rn(pz[k], cz));
                float nd = (p == f) ? 0.0f : fminf(dist[k], d);
                dist[k] = nd;
                unsigned long long kk = (((unsigned long long)__float_as_uint(nd)) << 32)
                                        | (unsigned)(0xFFFFFFFFu - (unsigned)p);
                if (kk > key) key = kk;
            }
        }
        EXCHANGE(i + 1)
    }
    __syncthreads();                           // centC fully written

    // ---- nearest-centroid assignment (centroids live in LDS) ----
    float* outClust = out + (size_t)BATCHES * NPOINT * 3 + (size_t)BATCHES * NPOINT;
    float bestd[KMAX]; int besti[KMAX];
    #pragma unroll
    for (int k = 0; k < KMAX; k++) { bestd[k] = 3.4e38f; besti[k] = 0; }
    for (int j = 0; j < NPOINT; j++) {
        float cx = centC[j][0], cy = centC[j][1], cz = centC[j][2];
        #pragma unroll
        for (int k = 0; k < KMAX; k++) {
            if (k < nk) {
                float d = sq3(__fsub_rn(px[k], cx), __fsub_rn(py[k], cy), __fsub_rn(pz[k], cz));
                if (d < bestd[k]) { bestd[k] = d; besti[k] = j; }   // strict < => first-index argmin
            }
        }
    }
    #pragma unroll
    for (int k = 0; k < KMAX; k++)
        if (k < nk) outClust[(size_t)b * NPTS + t + k * TPB] = (float)besti[k];
}

extern "C" void kernel_launch(void* const* d_in, const int* in_sizes, int n_in,
                              void* d_out, int out_size, void* d_ws, size_t ws_size,
                              hipStream_t stream) {
    const float* xyz = (const float*)d_in[0];
    float* out = (float*)d_out;
    hipMemsetAsync(d_ws, 0, WS_CTRL_BYTES, stream);   // slots + counters + partials
    fps_kernel<<<dim3(BATCHES * BPB), dim3(NTHREADS), 0, stream>>>(
        xyz, out, (unsigned char*)d_ws);
}